// Round 4
// baseline (121.821 us; speedup 1.0000x reference)
//
#include <hip/hip_runtime.h>

// Cost volume: out (B, 2C, D, H, W), fp32
//   c <  C : out = (w>=d) ? ref[b][c][h][w]     : 0
//   c >= C : out = (w>=d) ? tgt[b][c-C][h][w-d] : 0
// B=4, C=32, H=64, W=128, D=48. Output ~402.7 MB -> write-BW bound.
//
// R3: one block per (bc, d) plane -> fully linear 32 KB write sweep per block
// (8 passes x 4 KB; each wave-inst stores 1 KB contiguous). d is block-uniform:
// ref mask precomputed; tgt path splits into {full load | boundary | zero-store}
// classes that are constant per thread across all 8 passes.

constexpr int CV_B = 4;
constexpr int CV_C = 32;
constexpr int CV_H = 64;
constexpr int CV_W = 128;
constexpr int CV_D = 48;

typedef float floatx4 __attribute__((ext_vector_type(4)));

__global__ __launch_bounds__(256) void cost_volume_kernel(
    const float* __restrict__ ref,
    const float* __restrict__ tgt,
    floatx4* __restrict__ out)
{
    const int tid = threadIdx.x;
    const int d   = blockIdx.x;               // [0,48)  block-uniform
    const int bc  = blockIdx.y;               // [0,128) = b*64 + c2
    const int b   = bc >> 6;
    const int c2  = bc & 63;

    const bool is_tgt = (c2 >= CV_C);
    const int  c      = is_tgt ? (c2 - CV_C) : c2;

    const int w4 = tid & 31;                  // float4 column [0,32)
    const int hs = tid >> 5;                  // row-within-pass [0,8)
    const int w0 = w4 << 2;

    const float* __restrict__ src =
        (is_tgt ? tgt : ref) + (b * CV_C + c) * (CV_H * CV_W);

    // output plane (bc, d): 2048 float4, written linearly in 8 passes of 256
    floatx4* __restrict__ o = out + (((bc * CV_D + d)) << 11) + tid;

    if (!is_tgt) {
        // ref half: mask depends only on (w0, d) -> constant across passes
        const bool mx = (w0 + 0 >= d);
        const bool my = (w0 + 1 >= d);
        const bool mz = (w0 + 2 >= d);
        const bool mw = (w0 + 3 >= d);
#pragma unroll
        for (int k = 0; k < 8; ++k) {
            const int h = (k << 3) + hs;
            const floatx4 v =
                *reinterpret_cast<const floatx4*>(src + h * CV_W + w0);
            floatx4 r;
            r.x = mx ? v.x : 0.0f;
            r.y = my ? v.y : 0.0f;
            r.z = mz ? v.z : 0.0f;
            r.w = mw ? v.w : 0.0f;
            __builtin_nontemporal_store(r, o + (k << 8));
        }
    } else {
        const int s = w0 - d;                 // constant across passes
        if (s >= 0) {
            // full 16B load (dwordx4 needs only 4B alignment)
#pragma unroll
            for (int k = 0; k < 8; ++k) {
                const int h = (k << 3) + hs;
                const floatx4 v =
                    *reinterpret_cast<const floatx4*>(src + h * CV_W + s);
                __builtin_nontemporal_store(v, o + (k << 8));
            }
        } else if (s > -4) {
            // boundary float4: elements j >= -s are valid
#pragma unroll
            for (int k = 0; k < 8; ++k) {
                const int h = (k << 3) + hs;
                const float* row = src + h * CV_W;
                floatx4 r;
#pragma unroll
                for (int j = 0; j < 4; ++j)
                    r[j] = (s + j >= 0) ? row[s + j] : 0.0f;
                __builtin_nontemporal_store(r, o + (k << 8));
            }
        } else {
            // fully masked: zero-store, no load
            const floatx4 z = {0.0f, 0.0f, 0.0f, 0.0f};
#pragma unroll
            for (int k = 0; k < 8; ++k)
                __builtin_nontemporal_store(z, o + (k << 8));
        }
    }
}

extern "C" void kernel_launch(void* const* d_in, const int* in_sizes, int n_in,
                              void* d_out, int out_size, void* d_ws, size_t ws_size,
                              hipStream_t stream)
{
    const float* ref = (const float*)d_in[0];
    const float* tgt = (const float*)d_in[1];
    floatx4* out = (floatx4*)d_out;

    dim3 block(256);
    dim3 grid(CV_D, CV_B * 2 * CV_C);         // (48, 128) = 6144 blocks
    cost_volume_kernel<<<grid, block, 0, stream>>>(ref, tgt, out);
}

// Round 5
// 72.632 us; speedup vs baseline: 1.6772x; 1.6772x over previous
//
#include <hip/hip_runtime.h>

// Cost volume: out (B, 2C, D, H, W), fp32
//   c <  C : out = (w>=d) ? ref[b][c][h][w]     : 0
//   c >= C : out = (w>=d) ? tgt[b][c-C][h][w-d] : 0
// B=4, C=32, H=64, W=128, D=48. Output ~402.7 MB -> write-BW bound.
//
// R4: exact R2 structure (the 69.8 us winner; R3's plane-linear restructure
// regressed to 121.8), single delta: PLAIN stores instead of nontemporal.
// Rationale: fillBuffer hits 6.8-7.0 TB/s with plain stores; NT bypasses L2
// write-buffering. Write-allocate pollution is harmless (each input row is
// read by exactly one block; stores fully cover lines -> no RMW).

constexpr int CV_B = 4;
constexpr int CV_C = 32;
constexpr int CV_H = 64;
constexpr int CV_W = 128;
constexpr int CV_D = 48;

typedef float floatx4 __attribute__((ext_vector_type(4)));

__global__ __launch_bounds__(256) void cost_volume_kernel(
    const float* __restrict__ ref,
    const float* __restrict__ tgt,
    floatx4* __restrict__ out)
{
    const int w4 = threadIdx.x & 31;          // float4 index within row [0,32)
    const int d0 = threadIdx.x >> 5;          // base disparity [0,8)
    const int h  = blockIdx.x & (CV_H - 1);
    const int bc = blockIdx.x >> 6;           // b*64 + c2, c2 in [0,64)
    const int b  = bc >> 6;
    const int c2 = bc & 63;

    const bool is_tgt = (c2 >= CV_C);
    const int  c      = is_tgt ? (c2 - CV_C) : c2;

    const float* __restrict__ src =
        (is_tgt ? tgt : ref) + ((b * CV_C + c) * CV_H + h) * CV_W;

    const int w0 = w4 << 2;                   // first w of this float4

    // out float4 index for d = d0: ((bc*D + d0)*H + h)*32 + w4
    floatx4* __restrict__ o =
        out + (((bc * CV_D + d0) * CV_H + h) << 5) + w4;
    constexpr int OSTRIDE = 8 * CV_H * (CV_W / 4);   // d += 8, in float4 units

    if (!is_tgt) {
        // ref half: same source float4 for every d, just re-mask.
        const floatx4 v = *reinterpret_cast<const floatx4*>(src + w0);
#pragma unroll
        for (int k = 0; k < 6; ++k) {
            const int d = d0 + (k << 3);
            floatx4 r;
            r.x = (w0 + 0 >= d) ? v.x : 0.0f;
            r.y = (w0 + 1 >= d) ? v.y : 0.0f;
            r.z = (w0 + 2 >= d) ? v.z : 0.0f;
            r.w = (w0 + 3 >= d) ? v.w : 0.0f;
            o[k * OSTRIDE] = r;
        }
    } else {
        // tgt half: shifted window per d.
#pragma unroll
        for (int k = 0; k < 6; ++k) {
            const int d = d0 + (k << 3);
            const int s = w0 - d;             // source start for this float4
            floatx4 r;
            if (s >= 0) {
                // dword-aligned 16B load (gfx9 dwordx4 needs only 4B align)
                r = *reinterpret_cast<const floatx4*>(src + s);
            } else {
                floatx4 a;
#pragma unroll
                for (int j = 0; j < 4; ++j)
                    a[j] = (s + j >= 0) ? src[s + j] : 0.0f;
                r = a;
            }
            o[k * OSTRIDE] = r;
        }
    }
}

extern "C" void kernel_launch(void* const* d_in, const int* in_sizes, int n_in,
                              void* d_out, int out_size, void* d_ws, size_t ws_size,
                              hipStream_t stream)
{
    const float* ref = (const float*)d_in[0];
    const float* tgt = (const float*)d_in[1];
    floatx4* out = (floatx4*)d_out;

    dim3 block(256);
    dim3 grid(CV_B * 2 * CV_C * CV_H);        // one block per (bc, h) = 16384
    cost_volume_kernel<<<grid, block, 0, stream>>>(ref, tgt, out);
}

// Round 6
// 69.486 us; speedup vs baseline: 1.7532x; 1.0453x over previous
//
#include <hip/hip_runtime.h>

// Cost volume: out (B, 2C, D, H, W), fp32
//   c <  C : out = (w>=d) ? ref[b][c][h][w]     : 0
//   c >= C : out = (w>=d) ? tgt[b][c-C][h][w-d] : 0
// B=4, C=32, H=64, W=128, D=48. Output ~402.7 MB -> write-BW bound.
//
// R5: restore R2 exactly (best: 69.8 us = ~5.8 TB/s write stream).
// Ablation history: R3 plane-linear-writes restructure -> 121.8 us (regressed);
// R4 plain (non-NT) stores -> 72.6 us (regressed). NT no-allocate stores win:
// the 403 MB output is never re-read, so bypassing L2 fill is free bandwidth.
// Structure: one block per (bc, h) source row; thread owns (w4, d0), loops 6
// d-values (d = d0 + 8k). ref half: 1 float4 load reused 6x with cheap selects.
// tgt half: 1 dword-aligned dwordx4 load per store; boundary handled scalar.

constexpr int CV_B = 4;
constexpr int CV_C = 32;
constexpr int CV_H = 64;
constexpr int CV_W = 128;
constexpr int CV_D = 48;

typedef float floatx4 __attribute__((ext_vector_type(4)));

__global__ __launch_bounds__(256) void cost_volume_kernel(
    const float* __restrict__ ref,
    const float* __restrict__ tgt,
    floatx4* __restrict__ out)
{
    const int w4 = threadIdx.x & 31;          // float4 index within row [0,32)
    const int d0 = threadIdx.x >> 5;          // base disparity [0,8)
    const int h  = blockIdx.x & (CV_H - 1);
    const int bc = blockIdx.x >> 6;           // b*64 + c2, c2 in [0,64)
    const int b  = bc >> 6;
    const int c2 = bc & 63;

    const bool is_tgt = (c2 >= CV_C);
    const int  c      = is_tgt ? (c2 - CV_C) : c2;

    const float* __restrict__ src =
        (is_tgt ? tgt : ref) + ((b * CV_C + c) * CV_H + h) * CV_W;

    const int w0 = w4 << 2;                   // first w of this float4

    // out float4 index for d = d0: ((bc*D + d0)*H + h)*32 + w4
    floatx4* __restrict__ o =
        out + (((bc * CV_D + d0) * CV_H + h) << 5) + w4;
    constexpr int OSTRIDE = 8 * CV_H * (CV_W / 4);   // d += 8, in float4 units

    if (!is_tgt) {
        // ref half: same source float4 for every d, just re-mask.
        const floatx4 v = *reinterpret_cast<const floatx4*>(src + w0);
#pragma unroll
        for (int k = 0; k < 6; ++k) {
            const int d = d0 + (k << 3);
            floatx4 r;
            r.x = (w0 + 0 >= d) ? v.x : 0.0f;
            r.y = (w0 + 1 >= d) ? v.y : 0.0f;
            r.z = (w0 + 2 >= d) ? v.z : 0.0f;
            r.w = (w0 + 3 >= d) ? v.w : 0.0f;
            __builtin_nontemporal_store(r, o + k * OSTRIDE);
        }
    } else {
        // tgt half: shifted window per d.
#pragma unroll
        for (int k = 0; k < 6; ++k) {
            const int d = d0 + (k << 3);
            const int s = w0 - d;             // source start for this float4
            floatx4 r;
            if (s >= 0) {
                // dword-aligned 16B load (gfx9 dwordx4 needs only 4B align)
                r = *reinterpret_cast<const floatx4*>(src + s);
            } else {
                floatx4 a;
#pragma unroll
                for (int j = 0; j < 4; ++j)
                    a[j] = (s + j >= 0) ? src[s + j] : 0.0f;
                r = a;
            }
            __builtin_nontemporal_store(r, o + k * OSTRIDE);
        }
    }
}

extern "C" void kernel_launch(void* const* d_in, const int* in_sizes, int n_in,
                              void* d_out, int out_size, void* d_ws, size_t ws_size,
                              hipStream_t stream)
{
    const float* ref = (const float*)d_in[0];
    const float* tgt = (const float*)d_in[1];
    floatx4* out = (floatx4*)d_out;

    dim3 block(256);
    dim3 grid(CV_B * 2 * CV_C * CV_H);        // one block per (bc, h) = 16384
    cost_volume_kernel<<<grid, block, 0, stream>>>(ref, tgt, out);
}